// Round 6
// baseline (282.160 us; speedup 1.0000x reference)
//
#include <hip/hip_runtime.h>

// Problem constants (from reference): B,R,C,H,W = 4,2,19,256,512
constexpr int B = 4, R = 2, C = 19, H = 256, W = 512;
constexpr int HW = H * W;

// Output tile per block: 64 x 16 px; 256 threads, each thread = 4 consecutive x.
constexpr int BX = 64, BY = 16;
constexpr int NBX = W / BX;              // 8
constexpr int NBY = H / BY;              // 16
constexpr int NSPAT = B * NBX * NBY;     // 512 spatial tiles
// Channels split into 2 chunks (10 + 9) across gridDim.y -> 1024 blocks total.

// Pred tile staged in LDS per (channel, ref): halo 12 px (6 sigma of mv).
constexpr int TW = 92;                   // 64 + 2*12 + pair/floor slack, float4-aligned
constexpr int TH = 42;                   // 16 + 2*12 + slack
constexpr int TILE_N = TW * TH;          // 3864 floats = 15.46 KB
constexpr int TILE_V4 = TILE_N / 4;      // 966 float4s (TW/4 = 23 per row)

// NOTE: (256,2) not (256,4): the 64-VGPR cap from min-waves=4 spilled the
// 8xfloat4 prefetch buffer to scratch (R5: WRITE_SIZE 39->330 MB, dur 171us).
// 128 VGPRs -> 4 blocks/CU, which the 1024-block grid exactly fills.
__global__ __launch_bounds__(256, 2) void mc_warp_kernel(
    const float* __restrict__ pred,   // [B,R,C,H,W]
    const float* __restrict__ mv,     // [B,R,2,H,W] quarter-pel
    const float* __restrict__ wgt,    // [B,R,1,H,W]
    float* __restrict__ out)          // [B,C,H,W]
{
    __shared__ float tile0[TILE_N];
    __shared__ float tile1[TILE_N];

    int t = threadIdx.x;
    // XCD band swizzle on the spatial index: each XCD owns a contiguous
    // (b, y-band); both channel-chunks of a tile land on the same XCD
    // (gridDim.x = 512 is a multiple of 8).
    int xcd  = blockIdx.x & 7;
    int slot = blockIdx.x >> 3;
    int vblk = xcd * (NSPAT / 8) + slot;
    int bx   = vblk & (NBX - 1);
    int by   = (vblk >> 3) & (NBY - 1);
    int b    = vblk >> 7;
    int x0 = bx * BX, y0 = by * BY;
    int tx = t & 15, ty = t >> 4;
    int y  = y0 + ty;
    int xb = x0 + tx * 4;                 // first of this thread's 4 px

    // Tile origin, clamped fully inside the image (staging needs no clamps).
    int rowbase = min(max(y0 - 12, 0), H - TH);
    int colbase = min(max(x0 - 12, 0), W - TW);   // stays float4-aligned

    // Per-(ref, px) tap state: two row-pair offsets + 4 pair weights.
    int   off0[R][4], off1[R][4];
    int   offL0[R][4], offL1[R][4], offG0[R][4], offG1[R][4];
    float wq[R][4][4];
    int flag = 0;

    #pragma unroll
    for (int r = 0; r < R; ++r) {
        const float* mvp = mv + (size_t)((b * R + r) * 2) * HW + (size_t)y * W + xb;
        float4 mx4 = *(const float4*)(mvp);
        float4 my4 = *(const float4*)(mvp + HW);
        float4 wr4 = *(const float4*)(wgt + (size_t)(b * R + r) * HW + (size_t)y * W + xb);
        float mxs[4] = {mx4.x, mx4.y, mx4.z, mx4.w};
        float mys[4] = {my4.x, my4.y, my4.z, my4.w};
        float wrs[4] = {wr4.x, wr4.y, wr4.z, wr4.w};
        #pragma unroll
        for (int p = 0; p < 4; ++p) {
            int x = xb + p;
            float gx = (float)x + mxs[p] * 0.25f;   // quarter-pel -> pixel
            float gy = (float)y + mys[p] * 0.25f;
            float fx0 = floorf(gx), fy0 = floorf(gy);
            float wx1 = gx - fx0, wx0 = 1.0f - wx1;
            float wy1 = gy - fy0, wy0 = 1.0f - wy1;
            int ix0 = (int)fx0, iy0 = (int)fy0;
            int ix1 = ix0 + 1,  iy1 = iy0 + 1;

            // x pair: shift base into [0, W-2], route wx0/wx1 per element.
            int base = min(max(ix0, 0), W - 2);
            float wA = (ix0 == base)     ? wx0 : ((ix1 == base)     ? wx1 : 0.0f);
            float wB = (ix1 == base + 1) ? wx1 : ((ix0 == base + 1) ? wx0 : 0.0f);
            float wr = wrs[p];
            float wy0v = ((iy0 >= 0) && (iy0 < H)) ? wy0 * wr : 0.0f;
            float wy1v = ((iy1 >= 0) && (iy1 < H)) ? wy1 * wr : 0.0f;
            int cy0 = min(max(iy0, 0), H - 1);
            int cy1 = min(max(iy1, 0), H - 1);

            int l0 = base - colbase;
            int r0 = cy0 - rowbase, r1 = cy1 - rowbase;
            bool anyx = (wA != 0.0f) || (wB != 0.0f);
            bool anyy = (wy0v != 0.0f) || (wy1v != 0.0f);
            bool cb  = (l0 < 0 || l0 > TW - 2) && anyx && anyy;
            bool rb0 = (r0 < 0 || r0 > TH - 1) && (wy0v != 0.0f) && anyx;
            bool rb1 = (r1 < 0 || r1 > TH - 1) && (wy1v != 0.0f) && anyx;
            flag |= (int)(cb || rb0 || rb1);
            l0 = min(max(l0, 0), TW - 2);
            r0 = min(max(r0, 0), TH - 1);
            r1 = min(max(r1, 0), TH - 1);

            offL0[r][p] = r0 * TW + l0;
            offL1[r][p] = r1 * TW + l0;
            offG0[r][p] = cy0 * W + base;
            offG1[r][p] = cy1 * W + base;
            wq[r][p][0] = wy0v * wA;
            wq[r][p][1] = wy0v * wB;
            wq[r][p][2] = wy1v * wA;
            wq[r][p][3] = wy1v * wB;
        }
    }

    // Block-uniform fallback: if ANY tap escaped the halo (|mv| > ~12 px,
    // ~6 sigma), the whole block uses global gathers instead of LDS.
    int fbB = __syncthreads_or(flag);
    #pragma unroll
    for (int r = 0; r < R; ++r)
        #pragma unroll
        for (int p = 0; p < 4; ++p) {
            off0[r][p] = fbB ? offG0[r][p] : offL0[r][p];
            off1[r][p] = fbB ? offG1[r][p] : offL1[r][p];
        }

    const float* pl0 = pred + (size_t)(b * R + 0) * C * HW;
    const float* pl1 = pred + (size_t)(b * R + 1) * C * HW;
    const float* st0 = pl0 + (size_t)rowbase * W + colbase;
    const float* st1 = pl1 + (size_t)rowbase * W + colbase;
    float* ob = out + (size_t)b * C * HW + (size_t)y * W + xb;

    int cbeg = (blockIdx.y == 0) ? 0 : 10;
    int cend = (blockIdx.y == 0) ? 10 : 19;

    // Register double-buffer for staging: hold next channel's tile slice in
    // VGPRs so the global-load latency overlaps the previous channel's taps.
    float4 pf0[4], pf1[4];
    if (!fbB) {
        const float* s0 = st0 + (size_t)cbeg * HW;
        const float* s1 = st1 + (size_t)cbeg * HW;
        #pragma unroll
        for (int i = 0; i < 4; ++i) {
            int idx = t + i * 256;
            if (idx < TILE_V4) {
                int row = idx / 23;
                int col = (idx - row * 23) * 4;
                pf0[i] = *(const float4*)(s0 + row * W + col);
                pf1[i] = *(const float4*)(s1 + row * W + col);
            }
        }
    }

    for (int c = cbeg; c < cend; ++c) {
        float res[4];
        if (!fbB) {
            if (c > cbeg) __syncthreads();   // prior channel's LDS reads done
            // Drain prefetch registers into LDS (contiguous: addr = 4*idx).
            #pragma unroll
            for (int i = 0; i < 4; ++i) {
                int idx = t + i * 256;
                if (idx < TILE_V4) {
                    *(float4*)&tile0[4 * idx] = pf0[i];
                    *(float4*)&tile1[4 * idx] = pf1[i];
                }
            }
            __syncthreads();
            // Issue next channel's staging loads (consumed next round).
            if (c + 1 < cend) {
                const float* s0 = st0 + (size_t)(c + 1) * HW;
                const float* s1 = st1 + (size_t)(c + 1) * HW;
                #pragma unroll
                for (int i = 0; i < 4; ++i) {
                    int idx = t + i * 256;
                    if (idx < TILE_V4) {
                        int row = idx / 23;
                        int col = (idx - row * 23) * 4;
                        pf0[i] = *(const float4*)(s0 + row * W + col);
                        pf1[i] = *(const float4*)(s1 + row * W + col);
                    }
                }
            }
            #pragma unroll
            for (int p = 0; p < 4; ++p) {
                float a00 = tile0[off0[0][p]], a01 = tile0[off0[0][p] + 1];
                float a10 = tile0[off1[0][p]], a11 = tile0[off1[0][p] + 1];
                float b00 = tile1[off0[1][p]], b01 = tile1[off0[1][p] + 1];
                float b10 = tile1[off1[1][p]], b11 = tile1[off1[1][p] + 1];
                res[p] = wq[0][p][0] * a00 + wq[0][p][1] * a01
                       + wq[0][p][2] * a10 + wq[0][p][3] * a11
                       + wq[1][p][0] * b00 + wq[1][p][1] * b01
                       + wq[1][p][2] * b10 + wq[1][p][3] * b11;
            }
        } else {
            const float* pc0 = pl0 + (size_t)c * HW;
            const float* pc1 = pl1 + (size_t)c * HW;
            #pragma unroll
            for (int p = 0; p < 4; ++p) {
                float a00 = pc0[off0[0][p]], a01 = pc0[off0[0][p] + 1];
                float a10 = pc0[off1[0][p]], a11 = pc0[off1[0][p] + 1];
                float b00 = pc1[off0[1][p]], b01 = pc1[off0[1][p] + 1];
                float b10 = pc1[off1[1][p]], b11 = pc1[off1[1][p] + 1];
                res[p] = wq[0][p][0] * a00 + wq[0][p][1] * a01
                       + wq[0][p][2] * a10 + wq[0][p][3] * a11
                       + wq[1][p][0] * b00 + wq[1][p][1] * b01
                       + wq[1][p][2] * b10 + wq[1][p][3] * b11;
            }
        }
        *(float4*)(ob + (size_t)c * HW) = make_float4(res[0], res[1], res[2], res[3]);
    }
}

extern "C" void kernel_launch(void* const* d_in, const int* in_sizes, int n_in,
                              void* d_out, int out_size, void* d_ws, size_t ws_size,
                              hipStream_t stream) {
    const float* pred = (const float*)d_in[0];   // [B,R,C,H,W] fp32
    const float* mv   = (const float*)d_in[1];   // [B,R,2,H,W] fp32
    const float* wgt  = (const float*)d_in[2];   // [B,R,1,H,W] fp32
    float* out = (float*)d_out;                  // [B,C,H,W] fp32

    dim3 grid(NSPAT, 2);                         // 512 spatial tiles x 2 channel chunks
    mc_warp_kernel<<<grid, dim3(256), 0, stream>>>(pred, mv, wgt, out);
}

// Round 7
// 153.797 us; speedup vs baseline: 1.8346x; 1.8346x over previous
//
#include <hip/hip_runtime.h>

// Problem constants (from reference): B,R,C,H,W = 4,2,19,256,512
constexpr int B = 4, R = 2, C = 19, H = 256, W = 512;
constexpr int HW = H * W;

// Output tile per block: 64 x 16 px; 256 threads, each thread = 4 consecutive x.
constexpr int BX = 64, BY = 16;
constexpr int NBX = W / BX;              // 8
constexpr int NBY = H / BY;              // 16
constexpr int NSPAT = B * NBX * NBY;     // 512 spatial tiles
// Channels split 10+9 across gridDim.y -> 1024 blocks = 4 blocks/CU.

// Pred tile staged in LDS per (channel, ref): halo 12 px (6 sigma of mv).
constexpr int TW = 92;                   // 64 + 2*12 + pair/floor slack, float4-aligned
constexpr int TH = 42;                   // 16 + 2*12 + slack
constexpr int TILE_N = TW * TH;          // 3864 floats = 15.46 KB
constexpr int TILE_V4 = TILE_N / 4;      // 966 float4s (TW/4 = 23 per row)

// R4 body (proven: VGPR 64, zero spill) + channel chunking for occupancy.
// DO NOT add register prefetch buffers here: R5/R6 showed the compiler
// pushes them (and tap state) to scratch -> 280+ MB WRITE_SIZE, 2.4x slower.
__global__ __launch_bounds__(256, 4) void mc_warp_kernel(
    const float* __restrict__ pred,   // [B,R,C,H,W]
    const float* __restrict__ mv,     // [B,R,2,H,W] quarter-pel
    const float* __restrict__ wgt,    // [B,R,1,H,W]
    float* __restrict__ out)          // [B,C,H,W]
{
    __shared__ float tile0[TILE_N];
    __shared__ float tile1[TILE_N];

    int t = threadIdx.x;
    // XCD band swizzle on the spatial index: each XCD owns a contiguous
    // (b, y-band); both channel-chunks of a tile land on the same XCD
    // (gridDim.x = 512 is a multiple of 8).
    int xcd  = blockIdx.x & 7;
    int slot = blockIdx.x >> 3;
    int vblk = xcd * (NSPAT / 8) + slot;
    int bx   = vblk & (NBX - 1);
    int by   = (vblk >> 3) & (NBY - 1);
    int b    = vblk >> 7;
    int x0 = bx * BX, y0 = by * BY;
    int tx = t & 15, ty = t >> 4;
    int y  = y0 + ty;
    int xb = x0 + tx * 4;                 // first of this thread's 4 px

    // Tile origin, clamped fully inside the image (staging needs no clamps).
    int rowbase = min(max(y0 - 12, 0), H - TH);
    int colbase = min(max(x0 - 12, 0), W - TW);   // stays float4-aligned

    // Per-(ref, px) tap state: two row-pair offsets + 4 pair weights.
    int   off0[R][4], off1[R][4];
    int   offL0[R][4], offL1[R][4], offG0[R][4], offG1[R][4];
    float wq[R][4][4];
    int flag = 0;

    #pragma unroll
    for (int r = 0; r < R; ++r) {
        const float* mvp = mv + (size_t)((b * R + r) * 2) * HW + (size_t)y * W + xb;
        float4 mx4 = *(const float4*)(mvp);
        float4 my4 = *(const float4*)(mvp + HW);
        float4 wr4 = *(const float4*)(wgt + (size_t)(b * R + r) * HW + (size_t)y * W + xb);
        float mxs[4] = {mx4.x, mx4.y, mx4.z, mx4.w};
        float mys[4] = {my4.x, my4.y, my4.z, my4.w};
        float wrs[4] = {wr4.x, wr4.y, wr4.z, wr4.w};
        #pragma unroll
        for (int p = 0; p < 4; ++p) {
            int x = xb + p;
            float gx = (float)x + mxs[p] * 0.25f;   // quarter-pel -> pixel
            float gy = (float)y + mys[p] * 0.25f;
            float fx0 = floorf(gx), fy0 = floorf(gy);
            float wx1 = gx - fx0, wx0 = 1.0f - wx1;
            float wy1 = gy - fy0, wy0 = 1.0f - wy1;
            int ix0 = (int)fx0, iy0 = (int)fy0;
            int ix1 = ix0 + 1,  iy1 = iy0 + 1;

            // x pair: shift base into [0, W-2], route wx0/wx1 per element.
            int base = min(max(ix0, 0), W - 2);
            float wA = (ix0 == base)     ? wx0 : ((ix1 == base)     ? wx1 : 0.0f);
            float wB = (ix1 == base + 1) ? wx1 : ((ix0 == base + 1) ? wx0 : 0.0f);
            float wr = wrs[p];
            float wy0v = ((iy0 >= 0) && (iy0 < H)) ? wy0 * wr : 0.0f;
            float wy1v = ((iy1 >= 0) && (iy1 < H)) ? wy1 * wr : 0.0f;
            int cy0 = min(max(iy0, 0), H - 1);
            int cy1 = min(max(iy1, 0), H - 1);

            int l0 = base - colbase;
            int r0 = cy0 - rowbase, r1 = cy1 - rowbase;
            bool anyx = (wA != 0.0f) || (wB != 0.0f);
            bool anyy = (wy0v != 0.0f) || (wy1v != 0.0f);
            bool cb  = (l0 < 0 || l0 > TW - 2) && anyx && anyy;
            bool rb0 = (r0 < 0 || r0 > TH - 1) && (wy0v != 0.0f) && anyx;
            bool rb1 = (r1 < 0 || r1 > TH - 1) && (wy1v != 0.0f) && anyx;
            flag |= (int)(cb || rb0 || rb1);
            l0 = min(max(l0, 0), TW - 2);
            r0 = min(max(r0, 0), TH - 1);
            r1 = min(max(r1, 0), TH - 1);

            offL0[r][p] = r0 * TW + l0;
            offL1[r][p] = r1 * TW + l0;
            offG0[r][p] = cy0 * W + base;
            offG1[r][p] = cy1 * W + base;
            wq[r][p][0] = wy0v * wA;
            wq[r][p][1] = wy0v * wB;
            wq[r][p][2] = wy1v * wA;
            wq[r][p][3] = wy1v * wB;
        }
    }

    // Block-uniform fallback: if ANY tap escaped the halo (|mv| > ~12 px,
    // ~6 sigma), the whole block uses global gathers instead of LDS.
    int fbB = __syncthreads_or(flag);
    #pragma unroll
    for (int r = 0; r < R; ++r)
        #pragma unroll
        for (int p = 0; p < 4; ++p) {
            off0[r][p] = fbB ? offG0[r][p] : offL0[r][p];
            off1[r][p] = fbB ? offG1[r][p] : offL1[r][p];
        }

    const float* pl0 = pred + (size_t)(b * R + 0) * C * HW;
    const float* pl1 = pred + (size_t)(b * R + 1) * C * HW;
    const float* st0 = pl0 + (size_t)rowbase * W + colbase;
    const float* st1 = pl1 + (size_t)rowbase * W + colbase;
    float* ob = out + (size_t)b * C * HW + (size_t)y * W + xb;

    int cbeg = (blockIdx.y == 0) ? 0 : 10;
    int cend = (blockIdx.y == 0) ? 10 : 19;

    for (int c = cbeg; c < cend; ++c) {
        if (c > cbeg) __syncthreads();   // previous channel's LDS reads done
        if (!fbB) {
            const float* s0 = st0 + (size_t)c * HW;
            const float* s1 = st1 + (size_t)c * HW;
            #pragma unroll
            for (int i = 0; i < 4; ++i) {
                int idx = t + i * 256;
                if (idx < TILE_V4) {
                    int row = idx / 23;              // 23 float4s per tile row
                    int c4  = (idx - row * 23) * 4;
                    float4 v0 = *(const float4*)(s0 + row * W + c4);
                    float4 v1 = *(const float4*)(s1 + row * W + c4);
                    *(float4*)&tile0[row * TW + c4] = v0;
                    *(float4*)&tile1[row * TW + c4] = v1;
                }
            }
        }
        __syncthreads();

        float res[4];
        if (!fbB) {
            #pragma unroll
            for (int p = 0; p < 4; ++p) {
                float a00 = tile0[off0[0][p]], a01 = tile0[off0[0][p] + 1];
                float a10 = tile0[off1[0][p]], a11 = tile0[off1[0][p] + 1];
                float b00 = tile1[off0[1][p]], b01 = tile1[off0[1][p] + 1];
                float b10 = tile1[off1[1][p]], b11 = tile1[off1[1][p] + 1];
                res[p] = wq[0][p][0] * a00 + wq[0][p][1] * a01
                       + wq[0][p][2] * a10 + wq[0][p][3] * a11
                       + wq[1][p][0] * b00 + wq[1][p][1] * b01
                       + wq[1][p][2] * b10 + wq[1][p][3] * b11;
            }
        } else {
            const float* pc0 = pl0 + (size_t)c * HW;
            const float* pc1 = pl1 + (size_t)c * HW;
            #pragma unroll
            for (int p = 0; p < 4; ++p) {
                float a00 = pc0[off0[0][p]], a01 = pc0[off0[0][p] + 1];
                float a10 = pc0[off1[0][p]], a11 = pc0[off1[0][p] + 1];
                float b00 = pc1[off0[1][p]], b01 = pc1[off0[1][p] + 1];
                float b10 = pc1[off1[1][p]], b11 = pc1[off1[1][p] + 1];
                res[p] = wq[0][p][0] * a00 + wq[0][p][1] * a01
                       + wq[0][p][2] * a10 + wq[0][p][3] * a11
                       + wq[1][p][0] * b00 + wq[1][p][1] * b01
                       + wq[1][p][2] * b10 + wq[1][p][3] * b11;
            }
        }
        *(float4*)(ob + (size_t)c * HW) = make_float4(res[0], res[1], res[2], res[3]);
    }
}

extern "C" void kernel_launch(void* const* d_in, const int* in_sizes, int n_in,
                              void* d_out, int out_size, void* d_ws, size_t ws_size,
                              hipStream_t stream) {
    const float* pred = (const float*)d_in[0];   // [B,R,C,H,W] fp32
    const float* mv   = (const float*)d_in[1];   // [B,R,2,H,W] fp32
    const float* wgt  = (const float*)d_in[2];   // [B,R,1,H,W] fp32
    float* out = (float*)d_out;                  // [B,C,H,W] fp32

    dim3 grid(NSPAT, 2);                         // 512 spatial tiles x 2 channel chunks
    mc_warp_kernel<<<grid, dim3(256), 0, stream>>>(pred, mv, wgt, out);
}